// Round 14
// baseline (7288.763 us; speedup 1.0000x reference)
//
#include <hip/hip_runtime.h>

#define NFULL 33024
#define FPS_T 768
#define BST   99072    // per-batch stride in XYZ/S SoA: 3*33024
#define NTILE 516      // 516 tiles x 64 points
#define WTILE 43       // tiles per wave (12 waves x 43 = 516)

// ---- x1[b,o,k] = sum_i f[b,i] * ps_w[i,o,k] + ps_b[o] ; col = o*256+k ----
__global__ void k_ps(const float* __restrict__ feat,
                     const float* __restrict__ psw,
                     const float* __restrict__ psb,
                     float* __restrict__ out)
{
    __shared__ float fs[16384];   // all of f (32x512), 64 KB
    const int tid = threadIdx.x;
    for (int k = tid; k < 16384; k += 256) fs[k] = feat[k];
    __syncthreads();
    const int col = blockIdx.x * 256 + tid;    // 0..32767
    float acc[32];
    #pragma unroll
    for (int b = 0; b < 32; ++b) acc[b] = 0.f;
    for (int i = 0; i < 512; i += 4) {
        const float w0 = psw[(i+0)*32768 + col];
        const float w1 = psw[(i+1)*32768 + col];
        const float w2 = psw[(i+2)*32768 + col];
        const float w3 = psw[(i+3)*32768 + col];
        #pragma unroll
        for (int b = 0; b < 32; ++b) {
            const float4 f4 = *(const float4*)&fs[b*512 + i];
            acc[b] += f4.x*w0 + f4.y*w1 + f4.z*w2 + f4.w*w3;
        }
    }
    const float bias = psb[col >> 8];
    #pragma unroll
    for (int b = 0; b < 32; ++b) out[b*32768 + col] = acc[b] + bias;
}

// ---- fb[wsel][b,o] = sum_{i<512} f[b,i] * w[o*640 + 128 + i]  (fr-fold) ----
__global__ void k_fb(const float* __restrict__ feat,
                     const float* __restrict__ wa, const float* __restrict__ wb,
                     const float* __restrict__ wc, const float* __restrict__ wd,
                     float* __restrict__ fb)
{
    const int tid = blockIdx.x * 256 + threadIdx.x;  // 0..16383
    const int wsel = tid >> 12;
    const int r = tid & 4095;
    const int b = r >> 7, o = r & 127;
    const float* w = (wsel == 0 ? wa : wsel == 1 ? wb : wsel == 2 ? wc : wd) + o*640 + 128;
    const float* f = feat + b*512;
    float acc = 0.f;
    for (int i = 0; i < 512; i += 4) {
        const float4 wv = *(const float4*)(w + i);
        const float4 fv = *(const float4*)(f + i);
        acc += wv.x*fv.x + wv.y*fv.y + wv.z*fv.z + wv.w*fv.w;
    }
    fb[tid] = acc;
}

// ---- out[b,o,n] = relu?( sum_i w[o,i]*x[b,i,n] + bias[o] + fb[b,o] + add[b,o,n] )
__global__ void k_conv(const float* __restrict__ x,
                       const float* __restrict__ w,
                       const float* __restrict__ bias,
                       const float* __restrict__ fb,
                       const float* __restrict__ add,
                       float* __restrict__ out,
                       const int O, const int K, const int ldw, const int relu)
{
    const int bo = blockIdx.x;
    const int b = bo / O;
    const int o = bo - b * O;
    const int n = threadIdx.x;
    const float* __restrict__ wr = w + o * ldw;
    const float* __restrict__ xb = x + (b * K) * 256 + n;
    float acc = 0.f;
    for (int i = 0; i < K; i += 4) {
        const float4 wv = *(const float4*)(wr + i);
        acc += wv.x * xb[(i+0) << 8];
        acc += wv.y * xb[(i+1) << 8];
        acc += wv.z * xb[(i+2) << 8];
        acc += wv.w * xb[(i+3) << 8];
    }
    acc += bias[o];
    if (fb)   acc += fb[b * O + o];
    if (add)  acc += add[bo * 256 + n];
    if (relu) acc = fmaxf(acc, 0.f);
    out[bo * 256 + n] = acc;
}

// ---- pcd transpose -> d_out ; completion points -> XYZ SoA [0,256) ----
__global__ void k_pcd(const float* __restrict__ comp,
                      float* __restrict__ pcd_out,
                      float* __restrict__ XYZ)
{
    const int tid = blockIdx.x * 256 + threadIdx.x;  // 0..8191
    const int b = tid >> 8, n = tid & 255;
    const float cx = comp[(b*3+0)*256 + n];
    const float cy = comp[(b*3+1)*256 + n];
    const float cz = comp[(b*3+2)*256 + n];
    pcd_out[tid*3+0] = cx; pcd_out[tid*3+1] = cy; pcd_out[tid*3+2] = cz;
    float* Xb = XYZ + b*BST;
    Xb[n]           = cx;
    Xb[33024  + n]  = cy;
    Xb[66048  + n]  = cz;
}

// ---- partial (AoS) -> XYZ SoA [256,33024) per batch (bitwise) ----
__global__ void k_copy(const float* __restrict__ partial, float* __restrict__ XYZ)
{
    const int p = blockIdx.x*256 + threadIdx.x;   // 0..1048575 (32*32768)
    const int b = p >> 15, i = p & 32767;
    const float x = partial[p*3+0];
    const float y = partial[p*3+1];
    const float z = partial[p*3+2];
    float* Xb = XYZ + b*BST;
    Xb[256 + i]          = x;
    Xb[33024 + 256 + i]  = y;
    Xb[66048 + 256 + i]  = z;
}

// ================= spatial counting sort (per batch) =================
static __device__ __forceinline__ unsigned ordf(float f) {
    unsigned u = __float_as_uint(f);
    return (u & 0x80000000u) ? ~u : (u | 0x80000000u);
}
static __device__ __forceinline__ float unordf(unsigned u) {
    return __uint_as_float((u & 0x80000000u) ? (u & 0x7FFFFFFFu) : ~u);
}
static __device__ __forceinline__ unsigned mort3(unsigned ix, unsigned iy, unsigned iz) {
    unsigned m = 0;
    #pragma unroll
    for (int i = 0; i < 4; ++i)
        m |= (((ix>>i)&1u)<<(3*i)) | (((iy>>i)&1u)<<(3*i+1)) | (((iz>>i)&1u)<<(3*i+2));
    return m;   // 12-bit morton of 16^3 grid
}

__launch_bounds__(1024)
__global__ void k_sort(const float* __restrict__ XYZ, float* __restrict__ S,
                       int* __restrict__ OI, int* __restrict__ SP)
{
    __shared__ unsigned hist[4096];
    __shared__ unsigned base[4096];
    __shared__ unsigned sc[1024];
    __shared__ unsigned bb[6];
    __shared__ float bmn[3], bsc[3];

    const int b = blockIdx.x;
    const int t = threadIdx.x;
    const float* __restrict__ Xb = XYZ + b*BST;
    const float* __restrict__ Yb = Xb + NFULL;
    const float* __restrict__ Zb = Xb + 2*NFULL;

    for (int k = t; k < 4096; k += 1024) hist[k] = 0u;
    if (t < 3) { bb[t] = 0xFFFFFFFFu; bb[t+3] = 0u; }
    __syncthreads();

    // bbox (per-thread partial -> wave reduce -> LDS atomic on ordered uints)
    float mnx=1e30f, mny=1e30f, mnz=1e30f, mxx=-1e30f, mxy=-1e30f, mxz=-1e30f;
    for (int k = t; k < NFULL; k += 1024) {
        const float x = Xb[k], y = Yb[k], z = Zb[k];
        mnx = fminf(mnx,x); mny = fminf(mny,y); mnz = fminf(mnz,z);
        mxx = fmaxf(mxx,x); mxy = fmaxf(mxy,y); mxz = fmaxf(mxz,z);
    }
    #pragma unroll
    for (int m = 1; m < 64; m <<= 1) {
        mnx = fminf(mnx, __shfl_xor(mnx,m,64));
        mny = fminf(mny, __shfl_xor(mny,m,64));
        mnz = fminf(mnz, __shfl_xor(mnz,m,64));
        mxx = fmaxf(mxx, __shfl_xor(mxx,m,64));
        mxy = fmaxf(mxy, __shfl_xor(mxy,m,64));
        mxz = fmaxf(mxz, __shfl_xor(mxz,m,64));
    }
    if ((t & 63) == 0) {
        atomicMin(&bb[0], ordf(mnx)); atomicMin(&bb[1], ordf(mny)); atomicMin(&bb[2], ordf(mnz));
        atomicMax(&bb[3], ordf(mxx)); atomicMax(&bb[4], ordf(mxy)); atomicMax(&bb[5], ordf(mxz));
    }
    __syncthreads();
    if (t == 0) {
        #pragma unroll
        for (int d = 0; d < 3; ++d) {
            const float mn = unordf(bb[d]), mx = unordf(bb[d+3]);
            bmn[d] = mn;
            bsc[d] = 15.9999f / fmaxf(mx - mn, 1e-20f);
        }
    }
    __syncthreads();

    // histogram
    for (int k = t; k < NFULL; k += 1024) {
        const int ix = (int)((Xb[k]-bmn[0])*bsc[0]);
        const int iy = (int)((Yb[k]-bmn[1])*bsc[1]);
        const int iz = (int)((Zb[k]-bmn[2])*bsc[2]);
        atomicAdd(&hist[mort3((unsigned)ix,(unsigned)iy,(unsigned)iz)], 1u);
    }
    __syncthreads();

    // exclusive prefix (4/thread chunks + Hillis-Steele over 1024)
    const unsigned h0 = hist[4*t], h1 = hist[4*t+1], h2 = hist[4*t+2], h3 = hist[4*t+3];
    const unsigned s0 = h0+h1+h2+h3;
    sc[t] = s0; __syncthreads();
    for (int off = 1; off < 1024; off <<= 1) {
        const unsigned v = (t >= off) ? sc[t-off] : 0u;
        __syncthreads();
        sc[t] += v;
        __syncthreads();
    }
    unsigned run = sc[t] - s0;
    base[4*t] = run; run += h0;
    base[4*t+1] = run; run += h1;
    base[4*t+2] = run; run += h2;
    base[4*t+3] = run;
    __syncthreads();

    // scatter (order within cell nondeterministic -> output still exact:
    // argmax compares carried ORIGINAL indices, not layout order)
    float* __restrict__ Sx = S + b*BST;
    float* __restrict__ Sy = Sx + NFULL;
    float* __restrict__ Sz = Sx + 2*NFULL;
    int*   __restrict__ Ob = OI + b*NFULL;
    for (int k = t; k < NFULL; k += 1024) {
        const float x = Xb[k], y = Yb[k], z = Zb[k];
        const int ix = (int)((x-bmn[0])*bsc[0]);
        const int iy = (int)((y-bmn[1])*bsc[1]);
        const int iz = (int)((z-bmn[2])*bsc[2]);
        const unsigned pos = atomicAdd(&base[mort3((unsigned)ix,(unsigned)iy,(unsigned)iz)], 1u);
        Sx[pos] = x; Sy[pos] = y; Sz[pos] = z; Ob[pos] = k;
        if (k == 0) SP[b] = (int)pos;
    }
}

// ================= farthest point sampling (exact tile pruning) ==========
// One 768-thread block per batch. d in LDS (allocator-stable, r9). Points
// Morton-sorted -> 516 tiles of 64 spatially-tight points. Per tile: center,
// radius r_hi (upward slack), current (max d, first-max ORIG idx, sorted
// idx). Per step: screen tiles with lb = (max(0, D_lo - r_hi))^2 * (1-1e-5)
// where D_lo = sqrtf(distc2)*(1-1e-5); lb <= np_dist(p,c) for every p in
// tile (margins cover all fp32 rounding incl np's op order), so lb >=
// tile_max_d  =>  min(d, dist) == d for all p -> skip scan, record stays
// valid. Active tiles: bitwise-np-exact __f*_rn update + (value desc,
// orig-idx asc) reduce == np.argmax first-max. Worst case = full scan.

__launch_bounds__(FPS_T)
__global__ void k_fps(const float* __restrict__ S, const int* __restrict__ OI,
                      const int* __restrict__ SP, float* __restrict__ outp)
{
    __shared__ __align__(16) float dls[NFULL];   // 132,096 B
    __shared__ float tcx[NTILE], tcy[NTILE], tcz[NTILE], trr[NTILE];
    __shared__ float tmv[NTILE];
    __shared__ int   tmo[NTILE], tms[NTILE];
    __shared__ float redv[2][16];
    __shared__ int   redo_[2][16], reds[2][16];

    const int b = blockIdx.x;
    const int t = threadIdx.x;
    const int w = t >> 6;
    const int lane = t & 63;
    const int wbase = w * WTILE;
    const float* __restrict__ Xs = S + b*BST;
    const float* __restrict__ Ys = Xs + NFULL;
    const float* __restrict__ Zs = Xs + 2*NFULL;
    const int*   __restrict__ Ob = OI + b*NFULL;
    const float NEG = -__builtin_inff();

    // init: per-wave over its 43 tiles (center, radius, d=1e10, records)
    for (int i = 0; i < WTILE; ++i) {
        const int tt = wbase + i;
        const int p  = (tt << 6) + lane;
        const float xx = Xs[p], yy = Ys[p], zz = Zs[p];
        float sx = xx, sy = yy, sz = zz;
        #pragma unroll
        for (int m = 1; m < 64; m <<= 1) {
            sx += __shfl_xor(sx, m, 64);
            sy += __shfl_xor(sy, m, 64);
            sz += __shfl_xor(sz, m, 64);
        }
        const float cx = sx * 0.015625f, cy = sy * 0.015625f, cz = sz * 0.015625f;
        const float ex = xx - cx, ey = yy - cy, ez = zz - cz;
        float r2 = ex*ex + ey*ey + ez*ez;
        #pragma unroll
        for (int m = 1; m < 64; m <<= 1) r2 = fmaxf(r2, __shfl_xor(r2, m, 64));
        int oi = Ob[p], si = p;
        #pragma unroll
        for (int m = 1; m < 64; m <<= 1) {
            const int oo = __shfl_xor(oi, m, 64);
            const int os = __shfl_xor(si, m, 64);
            if (oo < oi) { oi = oo; si = os; }
        }
        dls[p] = 1.0e10f;
        if (lane == 0) {
            tcx[tt] = cx; tcy[tt] = cy; tcz[tt] = cz;
            trr[tt] = sqrtf(r2) * 1.00001f + 1e-12f;
            tmv[tt] = 1.0e10f; tmo[tt] = oi; tms[tt] = si;
        }
    }
    __syncthreads();

    int last = SP[b];                 // sorted position of original point 0
    float* __restrict__ po = outp + b * 1536;
    for (int s = 0; s < 512; ++s) {
        const float lx = Xs[last], ly = Ys[last], lz = Zs[last];
        if (t == 0) { po[s*3+0] = lx; po[s*3+1] = ly; po[s*3+2] = lz; }
        if (s == 511) break;

        // Phase A: conservative screening (lane i -> tile wbase+i)
        bool active = false;
        if (lane < WTILE) {
            const int tt = wbase + lane;
            const float ax = lx - tcx[tt], ay = ly - tcy[tt], az = lz - tcz[tt];
            const float Dc2 = ax*ax + ay*ay + az*az;
            const float Dlo = sqrtf(Dc2) * 0.99999f - trr[tt];
            active = true;
            if (Dlo > 0.f) active = (Dlo * Dlo * 0.99999f < tmv[tt]);
        }
        unsigned long long mask = __ballot(active);

        // Phase B: exact scan of active tiles (np-exact math, no fma)
        while (mask) {
            const int i = __builtin_ctzll(mask); mask &= mask - 1;
            const int tt = wbase + i;
            const int p  = (tt << 6) + lane;
            const float dx = __fsub_rn(Xs[p], lx);
            const float dy = __fsub_rn(Ys[p], ly);
            const float dz = __fsub_rn(Zs[p], lz);
            const float dist = __fadd_rn(__fadd_rn(__fmul_rn(dx,dx), __fmul_rn(dy,dy)),
                                         __fmul_rn(dz,dz));
            const float dd = fminf(dls[p], dist);
            dls[p] = dd;
            float v = dd; int oi = Ob[p]; int si = p;
            #pragma unroll
            for (int m = 1; m < 64; m <<= 1) {
                const float ov = __shfl_xor(v, m, 64);
                const int oo = __shfl_xor(oi, m, 64);
                const int os = __shfl_xor(si, m, 64);
                if (ov > v || (ov == v && oo < oi)) { v = ov; oi = oo; si = os; }
            }
            if (lane == 0) { tmv[tt] = v; tmo[tt] = oi; tms[tt] = si; }
        }
        __syncthreads();   // all tile records current

        // Phase C: block argmax over 516 records (value desc, orig idx asc)
        float v = NEG; int oi = 0x7FFFFFFF, si = 0;
        if (t < NTILE) { v = tmv[t]; oi = tmo[t]; si = tms[t]; }
        #pragma unroll
        for (int m = 1; m < 64; m <<= 1) {
            const float ov = __shfl_xor(v, m, 64);
            const int oo = __shfl_xor(oi, m, 64);
            const int os = __shfl_xor(si, m, 64);
            if (ov > v || (ov == v && oo < oi)) { v = ov; oi = oo; si = os; }
        }
        const int bank = s & 1;
        if (lane == 0) { redv[bank][w] = v; redo_[bank][w] = oi; reds[bank][w] = si; }
        __syncthreads();   // partials ready (parity-banked)
        {
            float vv = (lane < 12) ? redv[bank][lane] : NEG;
            int jo = (lane < 12) ? redo_[bank][lane] : 0x7FFFFFFF;
            int js = (lane < 12) ? reds[bank][lane] : 0;
            #pragma unroll
            for (int m = 1; m < 16; m <<= 1) {
                const float ov = __shfl_xor(vv, m, 64);
                const int oo = __shfl_xor(jo, m, 64);
                const int os = __shfl_xor(js, m, 64);
                if (ov > vv || (ov == vv && oo < jo)) { vv = ov; jo = oo; js = os; }
            }
            last = __shfl(js, 0, 64);
        }
    }
}

extern "C" void kernel_launch(void* const* d_in, const int* in_sizes, int n_in,
                              void* d_out, int out_size, void* d_ws, size_t ws_size,
                              hipStream_t stream)
{
    const float* feat    = (const float*)d_in[0];
    const float* partial = (const float*)d_in[1];
    const float* ps_w    = (const float*)d_in[2];
    const float* ps_b    = (const float*)d_in[3];
    const float* m1_w1   = (const float*)d_in[4];
    const float* m1_b1   = (const float*)d_in[5];
    const float* m1_w2   = (const float*)d_in[6];
    const float* m1_b2   = (const float*)d_in[7];
    const float* m1_ws   = (const float*)d_in[8];
    const float* m1_bs   = (const float*)d_in[9];
    const float* m2_w1   = (const float*)d_in[10];
    const float* m2_b1   = (const float*)d_in[11];
    const float* m2_w2   = (const float*)d_in[12];
    const float* m2_b2   = (const float*)d_in[13];
    const float* m2_ws   = (const float*)d_in[14];
    const float* m2_bs   = (const float*)d_in[15];
    const float* m3_w1   = (const float*)d_in[16];
    const float* m3_b1   = (const float*)d_in[17];
    const float* m3_w2   = (const float*)d_in[18];
    const float* m3_b2   = (const float*)d_in[19];
    const float* m3_ws   = (const float*)d_in[20];
    const float* m3_bs   = (const float*)d_in[21];
    const float* m4_w1   = (const float*)d_in[22];
    const float* m4_b1   = (const float*)d_in[23];
    const float* m4_w2   = (const float*)d_in[24];
    const float* m4_b2   = (const float*)d_in[25];

    float* ws = (float*)d_ws;
    float* XYZ = ws;               // 3,170,304 floats (SoA per batch)
    float* A  = ws + 3170304;      // 1,048,576
    float* B  = ws + 4218880;      // 1,048,576
    float* C  = ws + 5267456;      // 1,048,576
    float* FB = ws + 6316032;      // 16,384
    // S aliases A..FB region (convs and k_pcd finish before k_sort runs)
    float* S   = ws + 3170304;     // 3,170,304 floats (sorted SoA)
    int*   OIa = (int*)(ws + 6340608);   // 1,056,768 ints
    int*   SPa = (int*)(ws + 7397376);   // 32 ints

    float* out = (float*)d_out;   // [0,24576) pcd ; [24576,73728) p0

    k_ps  <<<128,  256, 0, stream>>>(feat, ps_w, ps_b, A);
    k_fb  <<<64,   256, 0, stream>>>(feat, m1_w1, m1_ws, m3_w1, m3_ws, FB);
    k_copy<<<4096, 256, 0, stream>>>(partial, XYZ);

    // m1 (fr folded into FB)
    k_conv<<<32*128, 256, 0, stream>>>(A, m1_w1, m1_b1, FB,       nullptr, B, 128, 128, 640, 1);
    k_conv<<<32*128, 256, 0, stream>>>(A, m1_ws, m1_bs, FB+4096,  nullptr, C, 128, 128, 640, 0);
    k_conv<<<32*128, 256, 0, stream>>>(B, m1_w2, m1_b2, nullptr,  C,       A, 128, 128, 128, 0);
    // m2
    k_conv<<<32*64,  256, 0, stream>>>(A, m2_w1, m2_b1, nullptr,  nullptr, B, 64,  128, 128, 1);
    k_conv<<<32*128, 256, 0, stream>>>(A, m2_ws, m2_bs, nullptr,  nullptr, C, 128, 128, 128, 0);
    k_conv<<<32*128, 256, 0, stream>>>(B, m2_w2, m2_b2, nullptr,  C,       A, 128, 64,  64,  0);
    // m3 (fr folded)
    k_conv<<<32*128, 256, 0, stream>>>(A, m3_w1, m3_b1, FB+8192,  nullptr, B, 128, 128, 640, 1);
    k_conv<<<32*128, 256, 0, stream>>>(A, m3_ws, m3_bs, FB+12288, nullptr, C, 128, 128, 640, 0);
    k_conv<<<32*128, 256, 0, stream>>>(B, m3_w2, m3_b2, nullptr,  C,       A, 128, 128, 128, 0);
    // m4
    k_conv<<<32*64,  256, 0, stream>>>(A, m4_w1, m4_b1, nullptr,  nullptr, B, 64,  128, 128, 1);
    k_conv<<<32*3,   256, 0, stream>>>(B, m4_w2, m4_b2, nullptr,  nullptr, C, 3,   64,  64,  0);

    k_pcd <<<32, 256, 0, stream>>>(C, out, XYZ);
    k_sort<<<32, 1024, 0, stream>>>(XYZ, S, OIa, SPa);
    k_fps <<<32, FPS_T, 0, stream>>>(S, OIa, SPa, out + 24576);
}

// Round 15
// 3599.036 us; speedup vs baseline: 2.0252x; 2.0252x over previous
//
#include <hip/hip_runtime.h>

#define NFULL 33024
#define FPS_T 768
#define BST   99072    // per-batch stride in XYZ/S SoA: 3*33024
#define NTILE 516      // 516 tiles x 64 points
#define NW    12       // waves per FPS block

// ---- x1[b,o,k] = sum_i f[b,i] * ps_w[i,o,k] + ps_b[o] ; col = o*256+k ----
__global__ void k_ps(const float* __restrict__ feat,
                     const float* __restrict__ psw,
                     const float* __restrict__ psb,
                     float* __restrict__ out)
{
    __shared__ float fs[16384];   // all of f (32x512), 64 KB
    const int tid = threadIdx.x;
    for (int k = tid; k < 16384; k += 256) fs[k] = feat[k];
    __syncthreads();
    const int col = blockIdx.x * 256 + tid;    // 0..32767
    float acc[32];
    #pragma unroll
    for (int b = 0; b < 32; ++b) acc[b] = 0.f;
    for (int i = 0; i < 512; i += 4) {
        const float w0 = psw[(i+0)*32768 + col];
        const float w1 = psw[(i+1)*32768 + col];
        const float w2 = psw[(i+2)*32768 + col];
        const float w3 = psw[(i+3)*32768 + col];
        #pragma unroll
        for (int b = 0; b < 32; ++b) {
            const float4 f4 = *(const float4*)&fs[b*512 + i];
            acc[b] += f4.x*w0 + f4.y*w1 + f4.z*w2 + f4.w*w3;
        }
    }
    const float bias = psb[col >> 8];
    #pragma unroll
    for (int b = 0; b < 32; ++b) out[b*32768 + col] = acc[b] + bias;
}

// ---- fb[wsel][b,o] = sum_{i<512} f[b,i] * w[o*640 + 128 + i]  (fr-fold) ----
__global__ void k_fb(const float* __restrict__ feat,
                     const float* __restrict__ wa, const float* __restrict__ wb,
                     const float* __restrict__ wc, const float* __restrict__ wd,
                     float* __restrict__ fb)
{
    const int tid = blockIdx.x * 256 + threadIdx.x;  // 0..16383
    const int wsel = tid >> 12;
    const int r = tid & 4095;
    const int b = r >> 7, o = r & 127;
    const float* w = (wsel == 0 ? wa : wsel == 1 ? wb : wsel == 2 ? wc : wd) + o*640 + 128;
    const float* f = feat + b*512;
    float acc = 0.f;
    for (int i = 0; i < 512; i += 4) {
        const float4 wv = *(const float4*)(w + i);
        const float4 fv = *(const float4*)(f + i);
        acc += wv.x*fv.x + wv.y*fv.y + wv.z*fv.z + wv.w*fv.w;
    }
    fb[tid] = acc;
}

// ---- out[b,o,n] = relu?( sum_i w[o,i]*x[b,i,n] + bias[o] + fb[b,o] + add[b,o,n] )
__global__ void k_conv(const float* __restrict__ x,
                       const float* __restrict__ w,
                       const float* __restrict__ bias,
                       const float* __restrict__ fb,
                       const float* __restrict__ add,
                       float* __restrict__ out,
                       const int O, const int K, const int ldw, const int relu)
{
    const int bo = blockIdx.x;
    const int b = bo / O;
    const int o = bo - b * O;
    const int n = threadIdx.x;
    const float* __restrict__ wr = w + o * ldw;
    const float* __restrict__ xb = x + (b * K) * 256 + n;
    float acc = 0.f;
    for (int i = 0; i < K; i += 4) {
        const float4 wv = *(const float4*)(wr + i);
        acc += wv.x * xb[(i+0) << 8];
        acc += wv.y * xb[(i+1) << 8];
        acc += wv.z * xb[(i+2) << 8];
        acc += wv.w * xb[(i+3) << 8];
    }
    acc += bias[o];
    if (fb)   acc += fb[b * O + o];
    if (add)  acc += add[bo * 256 + n];
    if (relu) acc = fmaxf(acc, 0.f);
    out[bo * 256 + n] = acc;
}

// ---- pcd transpose -> d_out ; completion points -> XYZ SoA [0,256) ----
__global__ void k_pcd(const float* __restrict__ comp,
                      float* __restrict__ pcd_out,
                      float* __restrict__ XYZ)
{
    const int tid = blockIdx.x * 256 + threadIdx.x;  // 0..8191
    const int b = tid >> 8, n = tid & 255;
    const float cx = comp[(b*3+0)*256 + n];
    const float cy = comp[(b*3+1)*256 + n];
    const float cz = comp[(b*3+2)*256 + n];
    pcd_out[tid*3+0] = cx; pcd_out[tid*3+1] = cy; pcd_out[tid*3+2] = cz;
    float* Xb = XYZ + b*BST;
    Xb[n]           = cx;
    Xb[33024  + n]  = cy;
    Xb[66048  + n]  = cz;
}

// ---- partial (AoS) -> XYZ SoA [256,33024) per batch (bitwise) ----
__global__ void k_copy(const float* __restrict__ partial, float* __restrict__ XYZ)
{
    const int p = blockIdx.x*256 + threadIdx.x;   // 0..1048575 (32*32768)
    const int b = p >> 15, i = p & 32767;
    const float x = partial[p*3+0];
    const float y = partial[p*3+1];
    const float z = partial[p*3+2];
    float* Xb = XYZ + b*BST;
    Xb[256 + i]          = x;
    Xb[33024 + 256 + i]  = y;
    Xb[66048 + 256 + i]  = z;
}

// ================= spatial counting sort (per batch) =================
static __device__ __forceinline__ unsigned ordf(float f) {
    unsigned u = __float_as_uint(f);
    return (u & 0x80000000u) ? ~u : (u | 0x80000000u);
}
static __device__ __forceinline__ float unordf(unsigned u) {
    return __uint_as_float((u & 0x80000000u) ? (u & 0x7FFFFFFFu) : ~u);
}
static __device__ __forceinline__ unsigned mort3(unsigned ix, unsigned iy, unsigned iz) {
    unsigned m = 0;
    #pragma unroll
    for (int i = 0; i < 4; ++i)
        m |= (((ix>>i)&1u)<<(3*i)) | (((iy>>i)&1u)<<(3*i+1)) | (((iz>>i)&1u)<<(3*i+2));
    return m;   // 12-bit morton of 16^3 grid
}

__launch_bounds__(1024)
__global__ void k_sort(const float* __restrict__ XYZ, float* __restrict__ S,
                       int* __restrict__ OI, int* __restrict__ SP)
{
    __shared__ unsigned hist[4096];
    __shared__ unsigned base[4096];
    __shared__ unsigned sc[1024];
    __shared__ unsigned bb[6];
    __shared__ float bmn[3], bsc[3];

    const int b = blockIdx.x;
    const int t = threadIdx.x;
    const float* __restrict__ Xb = XYZ + b*BST;
    const float* __restrict__ Yb = Xb + NFULL;
    const float* __restrict__ Zb = Xb + 2*NFULL;

    for (int k = t; k < 4096; k += 1024) hist[k] = 0u;
    if (t < 3) { bb[t] = 0xFFFFFFFFu; bb[t+3] = 0u; }
    __syncthreads();

    float mnx=1e30f, mny=1e30f, mnz=1e30f, mxx=-1e30f, mxy=-1e30f, mxz=-1e30f;
    for (int k = t; k < NFULL; k += 1024) {
        const float x = Xb[k], y = Yb[k], z = Zb[k];
        mnx = fminf(mnx,x); mny = fminf(mny,y); mnz = fminf(mnz,z);
        mxx = fmaxf(mxx,x); mxy = fmaxf(mxy,y); mxz = fmaxf(mxz,z);
    }
    #pragma unroll
    for (int m = 1; m < 64; m <<= 1) {
        mnx = fminf(mnx, __shfl_xor(mnx,m,64));
        mny = fminf(mny, __shfl_xor(mny,m,64));
        mnz = fminf(mnz, __shfl_xor(mnz,m,64));
        mxx = fmaxf(mxx, __shfl_xor(mxx,m,64));
        mxy = fmaxf(mxy, __shfl_xor(mxy,m,64));
        mxz = fmaxf(mxz, __shfl_xor(mxz,m,64));
    }
    if ((t & 63) == 0) {
        atomicMin(&bb[0], ordf(mnx)); atomicMin(&bb[1], ordf(mny)); atomicMin(&bb[2], ordf(mnz));
        atomicMax(&bb[3], ordf(mxx)); atomicMax(&bb[4], ordf(mxy)); atomicMax(&bb[5], ordf(mxz));
    }
    __syncthreads();
    if (t == 0) {
        #pragma unroll
        for (int d = 0; d < 3; ++d) {
            const float mn = unordf(bb[d]), mx = unordf(bb[d+3]);
            bmn[d] = mn;
            bsc[d] = 15.9999f / fmaxf(mx - mn, 1e-20f);
        }
    }
    __syncthreads();

    for (int k = t; k < NFULL; k += 1024) {
        const int ix = (int)((Xb[k]-bmn[0])*bsc[0]);
        const int iy = (int)((Yb[k]-bmn[1])*bsc[1]);
        const int iz = (int)((Zb[k]-bmn[2])*bsc[2]);
        atomicAdd(&hist[mort3((unsigned)ix,(unsigned)iy,(unsigned)iz)], 1u);
    }
    __syncthreads();

    const unsigned h0 = hist[4*t], h1 = hist[4*t+1], h2 = hist[4*t+2], h3 = hist[4*t+3];
    const unsigned s0 = h0+h1+h2+h3;
    sc[t] = s0; __syncthreads();
    for (int off = 1; off < 1024; off <<= 1) {
        const unsigned v = (t >= off) ? sc[t-off] : 0u;
        __syncthreads();
        sc[t] += v;
        __syncthreads();
    }
    unsigned run = sc[t] - s0;
    base[4*t] = run; run += h0;
    base[4*t+1] = run; run += h1;
    base[4*t+2] = run; run += h2;
    base[4*t+3] = run;
    __syncthreads();

    // scatter (order within cell nondeterministic -> still exact: argmax
    // ties use carried ORIGINAL indices, not layout order)
    float* __restrict__ Sx = S + b*BST;
    float* __restrict__ Sy = Sx + NFULL;
    float* __restrict__ Sz = Sx + 2*NFULL;
    int*   __restrict__ Ob = OI + b*NFULL;
    for (int k = t; k < NFULL; k += 1024) {
        const float x = Xb[k], y = Yb[k], z = Zb[k];
        const int ix = (int)((x-bmn[0])*bsc[0]);
        const int iy = (int)((y-bmn[1])*bsc[1]);
        const int iz = (int)((z-bmn[2])*bsc[2]);
        const unsigned pos = atomicAdd(&base[mort3((unsigned)ix,(unsigned)iy,(unsigned)iz)], 1u);
        Sx[pos] = x; Sy[pos] = y; Sz[pos] = z; Ob[pos] = k;
        if (k == 0) SP[b] = (int)pos;
    }
}

// ================= farthest point sampling (exact tile pruning v2) =======
// r14's pruning was exact but latency-dead: while(ctz(mask)) made each
// tile's loads a serial dependent chain (~0.5us x 43). v2 keeps the exact
// screening/records and fixes the SCHEDULE: Phase A compacts active tiles
// into an LDS worklist (atomicAdd, order-free); Phase B has wave w scan
// list[w], list[w+12], ... with next-iteration coord/d prefetch so loads
// overlap compute. Screening margins (1e-5 down on distance, 1e-5 up on
// radius) dominate all fp32 rounding incl np's op order => skipped tiles
// provably unchanged (min(d,dist)=d). Scanned tiles use bitwise-np-exact
// __f*_rn math; all reduces tie-break on ORIGINAL index => np.argmax
// first-max exactly. Worst case (all tiles active) ~= dense scan.

__launch_bounds__(FPS_T)
__global__ void k_fps(const float* __restrict__ S, const int* __restrict__ OI,
                      const int* __restrict__ SP, float* __restrict__ outp)
{
    __shared__ __align__(16) float dls[NFULL];   // 132,096 B
    __shared__ float tcx[NTILE], tcy[NTILE], tcz[NTILE], trr[NTILE];
    __shared__ float tmv[NTILE];
    __shared__ int   tmo[NTILE], tms[NTILE];
    __shared__ int   list[NTILE];
    __shared__ unsigned cnt;
    __shared__ float redv[2][16];
    __shared__ int   redo_[2][16], reds[2][16];

    const int b = blockIdx.x;
    const int t = threadIdx.x;
    const int w = t >> 6;
    const int lane = t & 63;
    const float* __restrict__ Xs = S + b*BST;
    const float* __restrict__ Ys = Xs + NFULL;
    const float* __restrict__ Zs = Xs + 2*NFULL;
    const int*   __restrict__ Ob = OI + b*NFULL;
    const float NEG = -__builtin_inff();

    // init: per-wave over its 43 tiles (center, radius, d=1e10, records)
    for (int i = w; i < NTILE; i += NW) {
        const int p = (i << 6) + lane;
        const float xx = Xs[p], yy = Ys[p], zz = Zs[p];
        float sx = xx, sy = yy, sz = zz;
        #pragma unroll
        for (int m = 1; m < 64; m <<= 1) {
            sx += __shfl_xor(sx, m, 64);
            sy += __shfl_xor(sy, m, 64);
            sz += __shfl_xor(sz, m, 64);
        }
        const float cx = sx * 0.015625f, cy = sy * 0.015625f, cz = sz * 0.015625f;
        const float ex = xx - cx, ey = yy - cy, ez = zz - cz;
        float r2 = ex*ex + ey*ey + ez*ez;
        #pragma unroll
        for (int m = 1; m < 64; m <<= 1) r2 = fmaxf(r2, __shfl_xor(r2, m, 64));
        int oi = Ob[p], si = p;
        #pragma unroll
        for (int m = 1; m < 64; m <<= 1) {
            const int oo = __shfl_xor(oi, m, 64);
            const int os = __shfl_xor(si, m, 64);
            if (oo < oi) { oi = oo; si = os; }
        }
        dls[p] = 1.0e10f;
        if (lane == 0) {
            tcx[i] = cx; tcy[i] = cy; tcz[i] = cz;
            trr[i] = sqrtf(r2) * 1.00001f + 1e-12f;
            tmv[i] = 1.0e10f; tmo[i] = oi; tms[i] = si;
        }
    }
    if (t == 0) cnt = 0u;
    __syncthreads();

    int last = SP[b];                 // sorted position of original point 0
    float* __restrict__ po = outp + b * 1536;
    for (int s = 0; s < 512; ++s) {
        const float lx = Xs[last], ly = Ys[last], lz = Zs[last];
        if (t == 0) { po[s*3+0] = lx; po[s*3+1] = ly; po[s*3+2] = lz; }
        if (s == 511) break;

        // Phase A: screen + compact worklist
        if (t < NTILE) {
            const float ax = lx - tcx[t], ay = ly - tcy[t], az = lz - tcz[t];
            const float Dc2 = ax*ax + ay*ay + az*az;
            const float Dlo = sqrtf(Dc2) * 0.99999f - trr[t];
            bool active = true;
            if (Dlo > 0.f) active = (Dlo * Dlo * 0.99999f < tmv[t]);
            if (active) { const unsigned pos = atomicAdd(&cnt, 1u); list[pos] = t; }
        }
        __syncthreads();                     // list/cnt ready
        const int n = (int)cnt;

        // Phase B: pipelined scan of worklist (wave-strided, prefetch next)
        {
            int i = w;
            int p0 = 0; float X0=0.f, Y0=0.f, Z0=0.f, D0=0.f; int tt0 = 0;
            if (i < n) {
                tt0 = list[i]; p0 = (tt0 << 6) + lane;
                X0 = Xs[p0]; Y0 = Ys[p0]; Z0 = Zs[p0]; D0 = dls[p0];
            }
            while (i < n) {
                const int i2 = i + NW;
                int p1 = 0, tt1 = 0; float X1=0.f, Y1=0.f, Z1=0.f, D1=0.f;
                if (i2 < n) {
                    tt1 = list[i2]; p1 = (tt1 << 6) + lane;
                    X1 = Xs[p1]; Y1 = Ys[p1]; Z1 = Zs[p1]; D1 = dls[p1];
                }
                // np-exact update of tile tt0
                const float dx = __fsub_rn(X0, lx);
                const float dy = __fsub_rn(Y0, ly);
                const float dz = __fsub_rn(Z0, lz);
                const float dist = __fadd_rn(__fadd_rn(__fmul_rn(dx,dx), __fmul_rn(dy,dy)),
                                             __fmul_rn(dz,dz));
                const float dd = fminf(D0, dist);
                dls[p0] = dd;
                float v = dd; int oi = Ob[p0]; int si = p0;
                #pragma unroll
                for (int m = 1; m < 64; m <<= 1) {
                    const float ov = __shfl_xor(v, m, 64);
                    const int oo = __shfl_xor(oi, m, 64);
                    const int os = __shfl_xor(si, m, 64);
                    if (ov > v || (ov == v && oo < oi)) { v = ov; oi = oo; si = os; }
                }
                if (lane == 0) { tmv[tt0] = v; tmo[tt0] = oi; tms[tt0] = si; }
                i = i2; tt0 = tt1; p0 = p1; X0 = X1; Y0 = Y1; Z0 = Z1; D0 = D1;
            }
        }
        __syncthreads();                     // tmv/tmo/tms current
        if (t == 0) cnt = 0u;                // reset for next step (pre-C-barrier)

        // Phase C: block argmax over 516 records (value desc, orig idx asc)
        float v = NEG; int oi = 0x7FFFFFFF, si = 0;
        if (t < NTILE) { v = tmv[t]; oi = tmo[t]; si = tms[t]; }
        #pragma unroll
        for (int m = 1; m < 64; m <<= 1) {
            const float ov = __shfl_xor(v, m, 64);
            const int oo = __shfl_xor(oi, m, 64);
            const int os = __shfl_xor(si, m, 64);
            if (ov > v || (ov == v && oo < oi)) { v = ov; oi = oo; si = os; }
        }
        const int bank = s & 1;
        if (lane == 0) { redv[bank][w] = v; redo_[bank][w] = oi; reds[bank][w] = si; }
        __syncthreads();                     // partials ready
        {
            float vv = (lane < NW) ? redv[bank][lane] : NEG;
            int jo = (lane < NW) ? redo_[bank][lane] : 0x7FFFFFFF;
            int js = (lane < NW) ? reds[bank][lane] : 0;
            #pragma unroll
            for (int m = 1; m < 16; m <<= 1) {
                const float ov = __shfl_xor(vv, m, 64);
                const int oo = __shfl_xor(jo, m, 64);
                const int os = __shfl_xor(js, m, 64);
                if (ov > vv || (ov == vv && oo < jo)) { vv = ov; jo = oo; js = os; }
            }
            last = __shfl(js, 0, 64);
        }
    }
}

extern "C" void kernel_launch(void* const* d_in, const int* in_sizes, int n_in,
                              void* d_out, int out_size, void* d_ws, size_t ws_size,
                              hipStream_t stream)
{
    const float* feat    = (const float*)d_in[0];
    const float* partial = (const float*)d_in[1];
    const float* ps_w    = (const float*)d_in[2];
    const float* ps_b    = (const float*)d_in[3];
    const float* m1_w1   = (const float*)d_in[4];
    const float* m1_b1   = (const float*)d_in[5];
    const float* m1_w2   = (const float*)d_in[6];
    const float* m1_b2   = (const float*)d_in[7];
    const float* m1_ws   = (const float*)d_in[8];
    const float* m1_bs   = (const float*)d_in[9];
    const float* m2_w1   = (const float*)d_in[10];
    const float* m2_b1   = (const float*)d_in[11];
    const float* m2_w2   = (const float*)d_in[12];
    const float* m2_b2   = (const float*)d_in[13];
    const float* m2_ws   = (const float*)d_in[14];
    const float* m2_bs   = (const float*)d_in[15];
    const float* m3_w1   = (const float*)d_in[16];
    const float* m3_b1   = (const float*)d_in[17];
    const float* m3_w2   = (const float*)d_in[18];
    const float* m3_b2   = (const float*)d_in[19];
    const float* m3_ws   = (const float*)d_in[20];
    const float* m3_bs   = (const float*)d_in[21];
    const float* m4_w1   = (const float*)d_in[22];
    const float* m4_b1   = (const float*)d_in[23];
    const float* m4_w2   = (const float*)d_in[24];
    const float* m4_b2   = (const float*)d_in[25];

    float* ws = (float*)d_ws;
    float* XYZ = ws;               // 3,170,304 floats (SoA per batch)
    float* A  = ws + 3170304;      // 1,048,576
    float* B  = ws + 4218880;      // 1,048,576
    float* C  = ws + 5267456;      // 1,048,576
    float* FB = ws + 6316032;      // 16,384
    // S aliases A..FB region (convs and k_pcd finish before k_sort runs)
    float* S   = ws + 3170304;     // 3,170,304 floats (sorted SoA)
    int*   OIa = (int*)(ws + 6340608);   // 1,056,768 ints
    int*   SPa = (int*)(ws + 7397376);   // 32 ints

    float* out = (float*)d_out;   // [0,24576) pcd ; [24576,73728) p0

    k_ps  <<<128,  256, 0, stream>>>(feat, ps_w, ps_b, A);
    k_fb  <<<64,   256, 0, stream>>>(feat, m1_w1, m1_ws, m3_w1, m3_ws, FB);
    k_copy<<<4096, 256, 0, stream>>>(partial, XYZ);

    // m1 (fr folded into FB)
    k_conv<<<32*128, 256, 0, stream>>>(A, m1_w1, m1_b1, FB,       nullptr, B, 128, 128, 640, 1);
    k_conv<<<32*128, 256, 0, stream>>>(A, m1_ws, m1_bs, FB+4096,  nullptr, C, 128, 128, 640, 0);
    k_conv<<<32*128, 256, 0, stream>>>(B, m1_w2, m1_b2, nullptr,  C,       A, 128, 128, 128, 0);
    // m2
    k_conv<<<32*64,  256, 0, stream>>>(A, m2_w1, m2_b1, nullptr,  nullptr, B, 64,  128, 128, 1);
    k_conv<<<32*128, 256, 0, stream>>>(A, m2_ws, m2_bs, nullptr,  nullptr, C, 128, 128, 128, 0);
    k_conv<<<32*128, 256, 0, stream>>>(B, m2_w2, m2_b2, nullptr,  C,       A, 128, 64,  64,  0);
    // m3 (fr folded)
    k_conv<<<32*128, 256, 0, stream>>>(A, m3_w1, m3_b1, FB+8192,  nullptr, B, 128, 128, 640, 1);
    k_conv<<<32*128, 256, 0, stream>>>(A, m3_ws, m3_bs, FB+12288, nullptr, C, 128, 128, 640, 0);
    k_conv<<<32*128, 256, 0, stream>>>(B, m3_w2, m3_b2, nullptr,  C,       A, 128, 128, 128, 0);
    // m4
    k_conv<<<32*64,  256, 0, stream>>>(A, m4_w1, m4_b1, nullptr,  nullptr, B, 64,  128, 128, 1);
    k_conv<<<32*3,   256, 0, stream>>>(B, m4_w2, m4_b2, nullptr,  nullptr, C, 3,   64,  64,  0);

    k_pcd <<<32, 256, 0, stream>>>(C, out, XYZ);
    k_sort<<<32, 1024, 0, stream>>>(XYZ, S, OIa, SPa);
    k_fps <<<32, FPS_T, 0, stream>>>(S, OIa, SPa, out + 24576);
}

// Round 16
// 3031.406 us; speedup vs baseline: 2.4044x; 1.1872x over previous
//
#include <hip/hip_runtime.h>

#define NFULL 33024
#define NVEC4 8256     // NFULL/4
#define BST   99072    // per-batch stride in XYZ SoA: 3*33024
#define FPS2_T 1024
#define CAP   6144     // max candidate-set size

// ---- x1[b,o,k] = sum_i f[b,i] * ps_w[i,o,k] + ps_b[o] ; col = o*256+k ----
__global__ void k_ps(const float* __restrict__ feat,
                     const float* __restrict__ psw,
                     const float* __restrict__ psb,
                     float* __restrict__ out)
{
    __shared__ float fs[16384];   // all of f (32x512), 64 KB
    const int tid = threadIdx.x;
    for (int k = tid; k < 16384; k += 256) fs[k] = feat[k];
    __syncthreads();
    const int col = blockIdx.x * 256 + tid;    // 0..32767
    float acc[32];
    #pragma unroll
    for (int b = 0; b < 32; ++b) acc[b] = 0.f;
    for (int i = 0; i < 512; i += 4) {
        const float w0 = psw[(i+0)*32768 + col];
        const float w1 = psw[(i+1)*32768 + col];
        const float w2 = psw[(i+2)*32768 + col];
        const float w3 = psw[(i+3)*32768 + col];
        #pragma unroll
        for (int b = 0; b < 32; ++b) {
            const float4 f4 = *(const float4*)&fs[b*512 + i];
            acc[b] += f4.x*w0 + f4.y*w1 + f4.z*w2 + f4.w*w3;
        }
    }
    const float bias = psb[col >> 8];
    #pragma unroll
    for (int b = 0; b < 32; ++b) out[b*32768 + col] = acc[b] + bias;
}

// ---- fb[wsel][b,o] = sum_{i<512} f[b,i] * w[o*640 + 128 + i]  (fr-fold) ----
__global__ void k_fb(const float* __restrict__ feat,
                     const float* __restrict__ wa, const float* __restrict__ wb,
                     const float* __restrict__ wc, const float* __restrict__ wd,
                     float* __restrict__ fb)
{
    const int tid = blockIdx.x * 256 + threadIdx.x;  // 0..16383
    const int wsel = tid >> 12;
    const int r = tid & 4095;
    const int b = r >> 7, o = r & 127;
    const float* w = (wsel == 0 ? wa : wsel == 1 ? wb : wsel == 2 ? wc : wd) + o*640 + 128;
    const float* f = feat + b*512;
    float acc = 0.f;
    for (int i = 0; i < 512; i += 4) {
        const float4 wv = *(const float4*)(w + i);
        const float4 fv = *(const float4*)(f + i);
        acc += wv.x*fv.x + wv.y*fv.y + wv.z*fv.z + wv.w*fv.w;
    }
    fb[tid] = acc;
}

// ---- out[b,o,n] = relu?( sum_i w[o,i]*x[b,i,n] + bias[o] + fb[b,o] + add[b,o,n] )
__global__ void k_conv(const float* __restrict__ x,
                       const float* __restrict__ w,
                       const float* __restrict__ bias,
                       const float* __restrict__ fb,
                       const float* __restrict__ add,
                       float* __restrict__ out,
                       const int O, const int K, const int ldw, const int relu)
{
    const int bo = blockIdx.x;
    const int b = bo / O;
    const int o = bo - b * O;
    const int n = threadIdx.x;
    const float* __restrict__ wr = w + o * ldw;
    const float* __restrict__ xb = x + (b * K) * 256 + n;
    float acc = 0.f;
    for (int i = 0; i < K; i += 4) {
        const float4 wv = *(const float4*)(wr + i);
        acc += wv.x * xb[(i+0) << 8];
        acc += wv.y * xb[(i+1) << 8];
        acc += wv.z * xb[(i+2) << 8];
        acc += wv.w * xb[(i+3) << 8];
    }
    acc += bias[o];
    if (fb)   acc += fb[b * O + o];
    if (add)  acc += add[bo * 256 + n];
    if (relu) acc = fmaxf(acc, 0.f);
    out[bo * 256 + n] = acc;
}

// ---- pcd transpose -> d_out ; completion points -> XYZ SoA [0,256) ----
__global__ void k_pcd(const float* __restrict__ comp,
                      float* __restrict__ pcd_out,
                      float* __restrict__ XYZ)
{
    const int tid = blockIdx.x * 256 + threadIdx.x;  // 0..8191
    const int b = tid >> 8, n = tid & 255;
    const float cx = comp[(b*3+0)*256 + n];
    const float cy = comp[(b*3+1)*256 + n];
    const float cz = comp[(b*3+2)*256 + n];
    pcd_out[tid*3+0] = cx; pcd_out[tid*3+1] = cy; pcd_out[tid*3+2] = cz;
    float* Xb = XYZ + b*BST;
    Xb[n]           = cx;
    Xb[33024  + n]  = cy;
    Xb[66048  + n]  = cz;
}

// ---- partial (AoS) -> XYZ SoA [256,33024) per batch (bitwise) ----
__global__ void k_copy(const float* __restrict__ partial, float* __restrict__ XYZ)
{
    const int p = blockIdx.x*256 + threadIdx.x;   // 0..1048575 (32*32768)
    const int b = p >> 15, i = p & 32767;
    const float x = partial[p*3+0];
    const float y = partial[p*3+1];
    const float z = partial[p*3+2];
    float* Xb = XYZ + b*BST;
    Xb[256 + i]          = x;
    Xb[33024 + 256 + i]  = y;
    Xb[66048 + 256 + i]  = z;
}

// ================= farthest point sampling (lazy batched rebuild) ========
// One 1024-thread block per batch. Exactness: d_p = min over centroids of
// np-dist (fp min is exact, commutative, no -0/NaN here) -> batching the
// min over deferred centroids is BITWISE identical to np's sequential min.
// Candidate set C = {p : d_p > theta} (theta = histogram rank-CAP bound).
// While selected max v > theta, non-candidates (d <= theta < v) can neither
// win nor tie -> winners computed from C alone (LDS, exact value+orig-idx
// argmax). When v <= theta: REBUILD = one streamed pass applying all
// pending centroids to all 33024 d's (order-free min), exact global argmax
// for this step's winner, histogram -> new theta (strict >, bin lower edge
// => |C| <= CAP guaranteed), recollect C. Degenerate C=empty just causes
// rebuild-per-step (correct, slower). Total update pairs = dense (each
// centroid applied once per point) but at VALU throughput, no per-step sync.

static __device__ __forceinline__ float npdist(float px, float py, float pz,
                                               float qx, float qy, float qz)
{
    const float dx = __fsub_rn(px, qx);
    const float dy = __fsub_rn(py, qy);
    const float dz = __fsub_rn(pz, qz);
    return __fadd_rn(__fadd_rn(__fmul_rn(dx,dx), __fmul_rn(dy,dy)),
                     __fmul_rn(dz,dz));
}

#define CPAK(CX, CY, CZ, CD, PP) { \
    const bool pr = ((CD) > theta); \
    const unsigned long long mb = __ballot(pr); \
    unsigned bs_ = 0u; \
    if (lane == 0) { const int c_ = __popcll(mb); if (c_) bs_ = atomicAdd(&ccnt, (unsigned)c_); } \
    bs_ = __shfl((int)bs_, 0, 64); \
    if (pr) { \
        const unsigned rk = __popcll(mb & ((1ull << lane) - 1ull)); \
        float4 e; e.x = (CX); e.y = (CY); e.z = (CZ); e.w = (CD); \
        candA[bs_ + rk] = e; coi_s[bs_ + rk] = (PP); \
    } }

__launch_bounds__(FPS2_T)
__global__ void k_fps(const float* __restrict__ XYZ, float* __restrict__ Dg,
                      float* __restrict__ outp)
{
    __shared__ float4  candA[CAP];          // (x,y,z,d) 98304 B
    __shared__ int     coi_s[CAP];          // orig idx  24576 B
    __shared__ unsigned hist[4096];         // 16384 B
    __shared__ unsigned sc[FPS2_T];         // 4096 B
    __shared__ float   pendx[512], pendy[512], pendz[512];  // 6144 B
    __shared__ float   redv[2][16], redx[2][16], redy[2][16], redz[2][16];
    __shared__ int     redi[2][16];
    __shared__ float   wx_s, wy_s, wz_s;
    __shared__ int     npend_s, bstar_s;
    __shared__ unsigned ccnt;

    const int b = blockIdx.x;
    const int t = threadIdx.x;
    const int w = t >> 6;
    const int lane = t & 63;
    const float* __restrict__ Xb = XYZ + b*BST;
    const float* __restrict__ Yb = Xb + NFULL;
    const float* __restrict__ Zb = Xb + 2*NFULL;
    float* __restrict__ Db = Dg + b*NFULL;
    float* __restrict__ po = outp + b * 1536;
    const float NEG = -__builtin_inff();

    // init: D = 1e10 (own slots), pending = {p0}, emit step 0
    {
        const float4 DI = make_float4(1.0e10f, 1.0e10f, 1.0e10f, 1.0e10f);
        for (int vi = t; vi < NVEC4; vi += FPS2_T) ((float4*)Db)[vi] = DI;
    }
    float wx = Xb[0], wy = Yb[0], wz = Zb[0];   // broadcast loads
    if (t == 0) {
        npend_s = 1;
        pendx[0] = wx; pendy[0] = wy; pendz[0] = wz;
        po[0] = wx; po[1] = wy; po[2] = wz;
    }
    float theta = NEG;   // forces rebuild at s=1
    int candN = 0;

    for (int s = 1; s < 512; ++s) {
        // ---- Phase A: update candidates with prev winner, cand argmax ----
        float v = NEG; int oi = 0x7FFFFFFF;
        float bx = 0.f, by = 0.f, bz = 0.f;
        for (int i = t; i < candN; i += FPS2_T) {
            float4 c4 = candA[i];
            const float dist = npdist(c4.x, c4.y, c4.z, wx, wy, wz);
            const float nd = fminf(c4.w, dist);
            ((float*)(&candA[i]))[3] = nd;
            const int io = coi_s[i];
            if (nd > v || (nd == v && io < oi)) { v = nd; oi = io; bx = c4.x; by = c4.y; bz = c4.z; }
        }
        #pragma unroll
        for (int m = 1; m < 64; m <<= 1) {
            const float ov = __shfl_xor(v, m, 64);
            const int   oo = __shfl_xor(oi, m, 64);
            const float ox = __shfl_xor(bx, m, 64);
            const float oy = __shfl_xor(by, m, 64);
            const float oz = __shfl_xor(bz, m, 64);
            if (ov > v || (ov == v && oo < oi)) { v = ov; oi = oo; bx = ox; by = oy; bz = oz; }
        }
        const int bank = s & 1;
        if (lane == 0) { redv[bank][w] = v; redi[bank][w] = oi;
                         redx[bank][w] = bx; redy[bank][w] = by; redz[bank][w] = bz; }
        __syncthreads();
        {
            float vv = (lane < 16) ? redv[bank][lane] : NEG;
            int   jo = (lane < 16) ? redi[bank][lane] : 0x7FFFFFFF;
            float jx = (lane < 16) ? redx[bank][lane] : 0.f;
            float jy = (lane < 16) ? redy[bank][lane] : 0.f;
            float jz = (lane < 16) ? redz[bank][lane] : 0.f;
            #pragma unroll
            for (int m = 1; m < 16; m <<= 1) {
                const float ov = __shfl_xor(vv, m, 64);
                const int   oo = __shfl_xor(jo, m, 64);
                const float ox = __shfl_xor(jx, m, 64);
                const float oy = __shfl_xor(jy, m, 64);
                const float oz = __shfl_xor(jz, m, 64);
                if (ov > vv || (ov == vv && oo < jo)) { vv = ov; jo = oo; jx = ox; jy = oy; jz = oz; }
            }
            v  = __shfl(vv, 0, 64);
            bx = __shfl(jx, 0, 64); by = __shfl(jy, 0, 64); bz = __shfl(jz, 0, 64);
        }

        if (v > theta) {
            // ---- candidate step: winner from C (exact) ----
            if (t == 0) {
                po[s*3+0] = bx; po[s*3+1] = by; po[s*3+2] = bz;
                const int np2 = npend_s;
                pendx[np2] = bx; pendy[np2] = by; pendz[np2] = bz;
                npend_s = np2 + 1;
            }
            wx = bx; wy = by; wz = bz;
        } else {
            // ---- REBUILD ----
            __syncthreads();                         // pend/npend visible
            const int np2 = npend_s;
            for (int k = t; k < 4096; k += FPS2_T) hist[k] = 0u;
            if (t == 0) { bstar_s = 0x7FFFFFFF; ccnt = 0u; }
            __syncthreads();

            float rv = NEG; int roi = 0x7FFFFFFF;
            for (int vi = t; vi < NVEC4; vi += FPS2_T) {
                const float4 X4 = ((const float4*)Xb)[vi];
                const float4 Y4 = ((const float4*)Yb)[vi];
                const float4 Z4 = ((const float4*)Zb)[vi];
                float4 D4 = ((float4*)Db)[vi];
                for (int j = 0; j < np2; ++j) {
                    const float qx = pendx[j], qy = pendy[j], qz = pendz[j];
                    D4.x = fminf(D4.x, npdist(X4.x, Y4.x, Z4.x, qx, qy, qz));
                    D4.y = fminf(D4.y, npdist(X4.y, Y4.y, Z4.y, qx, qy, qz));
                    D4.z = fminf(D4.z, npdist(X4.z, Y4.z, Z4.z, qx, qy, qz));
                    D4.w = fminf(D4.w, npdist(X4.w, Y4.w, Z4.w, qx, qy, qz));
                }
                ((float4*)Db)[vi] = D4;
                atomicAdd(&hist[__float_as_uint(D4.x) >> 19], 1u);
                atomicAdd(&hist[__float_as_uint(D4.y) >> 19], 1u);
                atomicAdd(&hist[__float_as_uint(D4.z) >> 19], 1u);
                atomicAdd(&hist[__float_as_uint(D4.w) >> 19], 1u);
                const int pp = vi << 2;
                if (D4.x > rv) { rv = D4.x; roi = pp; }
                if (D4.y > rv) { rv = D4.y; roi = pp + 1; }
                if (D4.z > rv) { rv = D4.z; roi = pp + 2; }
                if (D4.w > rv) { rv = D4.w; roi = pp + 3; }
            }
            __syncthreads();                         // hist complete
            // global argmax (value desc, orig idx asc)
            #pragma unroll
            for (int m = 1; m < 64; m <<= 1) {
                const float ov = __shfl_xor(rv, m, 64);
                const int   oo = __shfl_xor(roi, m, 64);
                if (ov > rv || (ov == rv && oo < roi)) { rv = ov; roi = oo; }
            }
            if (lane == 0) { redv[bank][w] = rv; redi[bank][w] = roi; }
            __syncthreads();
            {
                float vv = (lane < 16) ? redv[bank][lane] : NEG;
                int   jo = (lane < 16) ? redi[bank][lane] : 0x7FFFFFFF;
                #pragma unroll
                for (int m = 1; m < 16; m <<= 1) {
                    const float ov = __shfl_xor(vv, m, 64);
                    const int   oo = __shfl_xor(jo, m, 64);
                    if (ov > vv || (ov == vv && oo < jo)) { vv = ov; jo = oo; }
                }
                roi = __shfl(jo, 0, 64);
            }
            if (t == 0) { wx_s = Xb[roi]; wy_s = Yb[roi]; wz_s = Zb[roi]; }

            // suffix counts over 4096 bins -> theta (rank <= CAP, strict >)
            const unsigned h0 = hist[4*t+0], h1 = hist[4*t+1];
            const unsigned h2 = hist[4*t+2], h3 = hist[4*t+3];
            sc[t] = h0 + h1 + h2 + h3;
            __syncthreads();
            for (int off = 1; off < FPS2_T; off <<= 1) {
                const unsigned ad = (t + off < FPS2_T) ? sc[t + off] : 0u;
                __syncthreads();
                sc[t] += ad;
                __syncthreads();
            }
            const unsigned tail = (t < FPS2_T-1) ? sc[t+1] : 0u;
            const unsigned S3 = h3 + tail;
            const unsigned S2 = h2 + S3;
            const unsigned S1 = h1 + S2;
            const unsigned S0 = h0 + S1;
            int bb = 0x7FFFFFFF;
            if      (S0 <= CAP) bb = 4*t + 0;
            else if (S1 <= CAP) bb = 4*t + 1;
            else if (S2 <= CAP) bb = 4*t + 2;
            else if (S3 <= CAP) bb = 4*t + 3;
            if (bb != 0x7FFFFFFF) atomicMin(&bstar_s, bb);
            __syncthreads();
            const int bstar = bstar_s;
            theta = (bstar == 0x7FFFFFFF) ? __builtin_inff()
                                          : __uint_as_float((unsigned)bstar << 19);
            wx = wx_s; wy = wy_s; wz = wz_s;
            if (t == 0) {
                po[s*3+0] = wx; po[s*3+1] = wy; po[s*3+2] = wz;
                pendx[0] = wx; pendy[0] = wy; pendz[0] = wz;
                npend_s = 1;
            }
            // pass 2: collect C = {d > theta} (<= CAP by construction)
            for (int vi = t; vi < NVEC4; vi += FPS2_T) {
                const float4 X4 = ((const float4*)Xb)[vi];
                const float4 Y4 = ((const float4*)Yb)[vi];
                const float4 Z4 = ((const float4*)Zb)[vi];
                const float4 D4 = ((float4*)Db)[vi];
                const int pp = vi << 2;
                CPAK(X4.x, Y4.x, Z4.x, D4.x, pp + 0)
                CPAK(X4.y, Y4.y, Z4.y, D4.y, pp + 1)
                CPAK(X4.z, Y4.z, Z4.z, D4.z, pp + 2)
                CPAK(X4.w, Y4.w, Z4.w, D4.w, pp + 3)
            }
            __syncthreads();
            candN = (int)ccnt;
        }
    }
}

extern "C" void kernel_launch(void* const* d_in, const int* in_sizes, int n_in,
                              void* d_out, int out_size, void* d_ws, size_t ws_size,
                              hipStream_t stream)
{
    const float* feat    = (const float*)d_in[0];
    const float* partial = (const float*)d_in[1];
    const float* ps_w    = (const float*)d_in[2];
    const float* ps_b    = (const float*)d_in[3];
    const float* m1_w1   = (const float*)d_in[4];
    const float* m1_b1   = (const float*)d_in[5];
    const float* m1_w2   = (const float*)d_in[6];
    const float* m1_b2   = (const float*)d_in[7];
    const float* m1_ws   = (const float*)d_in[8];
    const float* m1_bs   = (const float*)d_in[9];
    const float* m2_w1   = (const float*)d_in[10];
    const float* m2_b1   = (const float*)d_in[11];
    const float* m2_w2   = (const float*)d_in[12];
    const float* m2_b2   = (const float*)d_in[13];
    const float* m2_ws   = (const float*)d_in[14];
    const float* m2_bs   = (const float*)d_in[15];
    const float* m3_w1   = (const float*)d_in[16];
    const float* m3_b1   = (const float*)d_in[17];
    const float* m3_w2   = (const float*)d_in[18];
    const float* m3_b2   = (const float*)d_in[19];
    const float* m3_ws   = (const float*)d_in[20];
    const float* m3_bs   = (const float*)d_in[21];
    const float* m4_w1   = (const float*)d_in[22];
    const float* m4_b1   = (const float*)d_in[23];
    const float* m4_w2   = (const float*)d_in[24];
    const float* m4_b2   = (const float*)d_in[25];

    float* ws = (float*)d_ws;
    float* XYZ = ws;               // 3,170,304 floats (SoA per batch)
    float* A  = ws + 3170304;      // 1,048,576
    float* B  = ws + 4218880;      // 1,048,576
    float* C  = ws + 5267456;      // 1,048,576
    float* FB = ws + 6316032;      // 16,384
    float* Dg = ws + 6332416;      // 32*33024 = 1,056,768 floats (d array)

    float* out = (float*)d_out;   // [0,24576) pcd ; [24576,73728) p0

    k_ps  <<<128,  256, 0, stream>>>(feat, ps_w, ps_b, A);
    k_fb  <<<64,   256, 0, stream>>>(feat, m1_w1, m1_ws, m3_w1, m3_ws, FB);
    k_copy<<<4096, 256, 0, stream>>>(partial, XYZ);

    // m1 (fr folded into FB)
    k_conv<<<32*128, 256, 0, stream>>>(A, m1_w1, m1_b1, FB,       nullptr, B, 128, 128, 640, 1);
    k_conv<<<32*128, 256, 0, stream>>>(A, m1_ws, m1_bs, FB+4096,  nullptr, C, 128, 128, 640, 0);
    k_conv<<<32*128, 256, 0, stream>>>(B, m1_w2, m1_b2, nullptr,  C,       A, 128, 128, 128, 0);
    // m2
    k_conv<<<32*64,  256, 0, stream>>>(A, m2_w1, m2_b1, nullptr,  nullptr, B, 64,  128, 128, 1);
    k_conv<<<32*128, 256, 0, stream>>>(A, m2_ws, m2_bs, nullptr,  nullptr, C, 128, 128, 128, 0);
    k_conv<<<32*128, 256, 0, stream>>>(B, m2_w2, m2_b2, nullptr,  C,       A, 128, 64,  64,  0);
    // m3 (fr folded)
    k_conv<<<32*128, 256, 0, stream>>>(A, m3_w1, m3_b1, FB+8192,  nullptr, B, 128, 128, 640, 1);
    k_conv<<<32*128, 256, 0, stream>>>(A, m3_ws, m3_bs, FB+12288, nullptr, C, 128, 128, 640, 0);
    k_conv<<<32*128, 256, 0, stream>>>(B, m3_w2, m3_b2, nullptr,  C,       A, 128, 128, 128, 0);
    // m4
    k_conv<<<32*64,  256, 0, stream>>>(A, m4_w1, m4_b1, nullptr,  nullptr, B, 64,  128, 128, 1);
    k_conv<<<32*3,   256, 0, stream>>>(B, m4_w2, m4_b2, nullptr,  nullptr, C, 3,   64,  64,  0);

    k_pcd <<<32, 256, 0, stream>>>(C, out, XYZ);
    k_fps <<<32, FPS2_T, 0, stream>>>(XYZ, Dg, out + 24576);
}

// Round 17
// 2821.476 us; speedup vs baseline: 2.5833x; 1.0744x over previous
//
#include <hip/hip_runtime.h>

#define NFULL 33024
#define NVEC4 8256     // NFULL/4
#define BST   99072    // per-batch stride in XYZ SoA: 3*33024
#define FPS2_T 512
#define NW2    8       // waves
#define CAP   6144     // max candidate-set size

// ---- x1[b,o,k] = sum_i f[b,i] * ps_w[i,o,k] + ps_b[o] ; col = o*256+k ----
__global__ void k_ps(const float* __restrict__ feat,
                     const float* __restrict__ psw,
                     const float* __restrict__ psb,
                     float* __restrict__ out)
{
    __shared__ float fs[16384];   // all of f (32x512), 64 KB
    const int tid = threadIdx.x;
    for (int k = tid; k < 16384; k += 256) fs[k] = feat[k];
    __syncthreads();
    const int col = blockIdx.x * 256 + tid;    // 0..32767
    float acc[32];
    #pragma unroll
    for (int b = 0; b < 32; ++b) acc[b] = 0.f;
    for (int i = 0; i < 512; i += 4) {
        const float w0 = psw[(i+0)*32768 + col];
        const float w1 = psw[(i+1)*32768 + col];
        const float w2 = psw[(i+2)*32768 + col];
        const float w3 = psw[(i+3)*32768 + col];
        #pragma unroll
        for (int b = 0; b < 32; ++b) {
            const float4 f4 = *(const float4*)&fs[b*512 + i];
            acc[b] += f4.x*w0 + f4.y*w1 + f4.z*w2 + f4.w*w3;
        }
    }
    const float bias = psb[col >> 8];
    #pragma unroll
    for (int b = 0; b < 32; ++b) out[b*32768 + col] = acc[b] + bias;
}

// ---- fb[wsel][b,o] = sum_{i<512} f[b,i] * w[o*640 + 128 + i]  (fr-fold) ----
__global__ void k_fb(const float* __restrict__ feat,
                     const float* __restrict__ wa, const float* __restrict__ wb,
                     const float* __restrict__ wc, const float* __restrict__ wd,
                     float* __restrict__ fb)
{
    const int tid = blockIdx.x * 256 + threadIdx.x;  // 0..16383
    const int wsel = tid >> 12;
    const int r = tid & 4095;
    const int b = r >> 7, o = r & 127;
    const float* w = (wsel == 0 ? wa : wsel == 1 ? wb : wsel == 2 ? wc : wd) + o*640 + 128;
    const float* f = feat + b*512;
    float acc = 0.f;
    for (int i = 0; i < 512; i += 4) {
        const float4 wv = *(const float4*)(w + i);
        const float4 fv = *(const float4*)(f + i);
        acc += wv.x*fv.x + wv.y*fv.y + wv.z*fv.z + wv.w*fv.w;
    }
    fb[tid] = acc;
}

// ---- out[b,o,n] = relu?( sum_i w[o,i]*x[b,i,n] + bias[o] + fb[b,o] + add[b,o,n] )
__global__ void k_conv(const float* __restrict__ x,
                       const float* __restrict__ w,
                       const float* __restrict__ bias,
                       const float* __restrict__ fb,
                       const float* __restrict__ add,
                       float* __restrict__ out,
                       const int O, const int K, const int ldw, const int relu)
{
    const int bo = blockIdx.x;
    const int b = bo / O;
    const int o = bo - b * O;
    const int n = threadIdx.x;
    const float* __restrict__ wr = w + o * ldw;
    const float* __restrict__ xb = x + (b * K) * 256 + n;
    float acc = 0.f;
    for (int i = 0; i < K; i += 4) {
        const float4 wv = *(const float4*)(wr + i);
        acc += wv.x * xb[(i+0) << 8];
        acc += wv.y * xb[(i+1) << 8];
        acc += wv.z * xb[(i+2) << 8];
        acc += wv.w * xb[(i+3) << 8];
    }
    acc += bias[o];
    if (fb)   acc += fb[b * O + o];
    if (add)  acc += add[bo * 256 + n];
    if (relu) acc = fmaxf(acc, 0.f);
    out[bo * 256 + n] = acc;
}

// ---- pcd transpose -> d_out ; completion points -> XYZ SoA [0,256) ----
__global__ void k_pcd(const float* __restrict__ comp,
                      float* __restrict__ pcd_out,
                      float* __restrict__ XYZ)
{
    const int tid = blockIdx.x * 256 + threadIdx.x;  // 0..8191
    const int b = tid >> 8, n = tid & 255;
    const float cx = comp[(b*3+0)*256 + n];
    const float cy = comp[(b*3+1)*256 + n];
    const float cz = comp[(b*3+2)*256 + n];
    pcd_out[tid*3+0] = cx; pcd_out[tid*3+1] = cy; pcd_out[tid*3+2] = cz;
    float* Xb = XYZ + b*BST;
    Xb[n]           = cx;
    Xb[33024  + n]  = cy;
    Xb[66048  + n]  = cz;
}

// ---- partial (AoS) -> XYZ SoA [256,33024) per batch (bitwise) ----
__global__ void k_copy(const float* __restrict__ partial, float* __restrict__ XYZ)
{
    const int p = blockIdx.x*256 + threadIdx.x;   // 0..1048575 (32*32768)
    const int b = p >> 15, i = p & 32767;
    const float x = partial[p*3+0];
    const float y = partial[p*3+1];
    const float z = partial[p*3+2];
    float* Xb = XYZ + b*BST;
    Xb[256 + i]          = x;
    Xb[33024 + 256 + i]  = y;
    Xb[66048 + 256 + i]  = z;
}

// ================= farthest point sampling (lazy batched rebuild v2) =====
// Same exact algorithm as r16 (passed). Mechanics fixed: T=512 (128-VGPR
// budget, 8-wave barriers), candidate SoA in flat float arrays (stride-4B,
// conflict-free; cd RMW is slot-private per thread), reduce carries only
// (v, origidx, slot) with winner coords via one uniform LDS read, ONE
// parity-banked barrier per candidate step. Exactness: fp min over the
// same multiset of np-dists is order-free/bitwise; candidate winners have
// v > theta >= all non-candidate d (strict); ties resolved by ORIGINAL
// index everywhere => np.argmax first-max exactly.

static __device__ __forceinline__ float npdist(float px, float py, float pz,
                                               float qx, float qy, float qz)
{
    const float dx = __fsub_rn(px, qx);
    const float dy = __fsub_rn(py, qy);
    const float dz = __fsub_rn(pz, qz);
    return __fadd_rn(__fadd_rn(__fmul_rn(dx,dx), __fmul_rn(dy,dy)),
                     __fmul_rn(dz,dz));
}

#define CPAK(CX, CY, CZ, CD, PP) { \
    const bool pr = ((CD) > theta); \
    const unsigned long long mb = __ballot(pr); \
    unsigned bs_ = 0u; \
    if (lane == 0) { const int c_ = __popcll(mb); if (c_) bs_ = atomicAdd(&ccnt, (unsigned)c_); } \
    bs_ = (unsigned)__shfl((int)bs_, 0, 64); \
    if (pr) { \
        const unsigned rk = __popcll(mb & ((1ull << lane) - 1ull)); \
        cx_s[bs_+rk] = (CX); cy_s[bs_+rk] = (CY); cz_s[bs_+rk] = (CZ); \
        cd_s[bs_+rk] = (CD); coi_s[bs_+rk] = (PP); \
    } }

__launch_bounds__(FPS2_T)
__global__ void k_fps(const float* __restrict__ XYZ, float* __restrict__ Dg,
                      float* __restrict__ outp)
{
    __shared__ float   cx_s[CAP], cy_s[CAP], cz_s[CAP], cd_s[CAP]; // 98304 B
    __shared__ int     coi_s[CAP];                                 // 24576 B
    __shared__ unsigned hist[4096];                                // 16384 B
    __shared__ unsigned sc[FPS2_T];                                //  2048 B
    __shared__ float   pendx[512], pendy[512], pendz[512];         //  6144 B
    __shared__ float   redv[2][NW2];
    __shared__ int     redi[2][NW2], redc[2][NW2];
    __shared__ float   wx_s, wy_s, wz_s;
    __shared__ int     npend_s, bstar_s;
    __shared__ unsigned ccnt;

    const int b = blockIdx.x;
    const int t = threadIdx.x;
    const int w = t >> 6;
    const int lane = t & 63;
    const float* __restrict__ Xb = XYZ + b*BST;
    const float* __restrict__ Yb = Xb + NFULL;
    const float* __restrict__ Zb = Xb + 2*NFULL;
    float* __restrict__ Db = Dg + b*NFULL;
    float* __restrict__ po = outp + b * 1536;
    const float NEG = -__builtin_inff();

    {   // init D = 1e10 (thread-strided slots, same mapping as rebuild)
        const float4 DI = make_float4(1.0e10f, 1.0e10f, 1.0e10f, 1.0e10f);
        for (int vi = t; vi < NVEC4; vi += FPS2_T) ((float4*)Db)[vi] = DI;
    }
    float wx = Xb[0], wy = Yb[0], wz = Zb[0];
    if (t == 0) {
        npend_s = 1;
        pendx[0] = wx; pendy[0] = wy; pendz[0] = wz;
        po[0] = wx; po[1] = wy; po[2] = wz;
    }
    float theta = NEG;   // forces rebuild at s=1
    int candN = 0;

    for (int s = 1; s < 512; ++s) {
        const int bank = s & 1;
        // ---- Phase A: update candidates with prev winner; local argmax ----
        float v = NEG; int oi = 0x7FFFFFFF, ci = 0;
        for (int i = t; i < candN; i += FPS2_T) {
            const float nd = fminf(cd_s[i], npdist(cx_s[i], cy_s[i], cz_s[i], wx, wy, wz));
            cd_s[i] = nd;                       // slot-private (i = t mod T)
            const int io = coi_s[i];
            if (nd > v || (nd == v && io < oi)) { v = nd; oi = io; ci = i; }
        }
        #pragma unroll
        for (int m = 1; m < 64; m <<= 1) {
            const float ov = __shfl_xor(v, m, 64);
            const int   oo = __shfl_xor(oi, m, 64);
            const int   oc = __shfl_xor(ci, m, 64);
            if (ov > v || (ov == v && oo < oi)) { v = ov; oi = oo; ci = oc; }
        }
        if (lane == 0) { redv[bank][w] = v; redi[bank][w] = oi; redc[bank][w] = ci; }
        __syncthreads();                        // the ONE candidate-step barrier
        {
            float vv = (lane < NW2) ? redv[bank][lane] : NEG;
            int   jo = (lane < NW2) ? redi[bank][lane] : 0x7FFFFFFF;
            int   jc = (lane < NW2) ? redc[bank][lane] : 0;
            #pragma unroll
            for (int m = 1; m < NW2; m <<= 1) {
                const float ov = __shfl_xor(vv, m, 64);
                const int   oo = __shfl_xor(jo, m, 64);
                const int   oc = __shfl_xor(jc, m, 64);
                if (ov > vv || (ov == vv && oo < jo)) { vv = ov; jo = oo; jc = oc; }
            }
            v  = __shfl(vv, 0, 64);
            ci = __shfl(jc, 0, 64);
        }

        if (v > theta) {
            // ---- candidate step: winner from C (exact) ----
            wx = cx_s[ci]; wy = cy_s[ci]; wz = cz_s[ci];   // uniform LDS read
            if (t == 0) {
                po[s*3+0] = wx; po[s*3+1] = wy; po[s*3+2] = wz;
                const int np2 = npend_s;
                pendx[np2] = wx; pendy[np2] = wy; pendz[np2] = wz;
                npend_s = np2 + 1;
            }
        } else {
            // ---- REBUILD ----
            const int np2 = npend_s;            // Phase-A barrier ordered this
            for (int k = t; k < 4096; k += FPS2_T) hist[k] = 0u;
            if (t == 0) { bstar_s = 0x7FFFFFFF; ccnt = 0u; }
            __syncthreads();

            float rv = NEG; int roi = 0x7FFFFFFF;
            for (int vi = t; vi < NVEC4; vi += FPS2_T) {
                const float4 X4 = ((const float4*)Xb)[vi];
                const float4 Y4 = ((const float4*)Yb)[vi];
                const float4 Z4 = ((const float4*)Zb)[vi];
                float4 D4 = ((float4*)Db)[vi];
                for (int j = 0; j < np2; ++j) {
                    const float qx = pendx[j], qy = pendy[j], qz = pendz[j];
                    D4.x = fminf(D4.x, npdist(X4.x, Y4.x, Z4.x, qx, qy, qz));
                    D4.y = fminf(D4.y, npdist(X4.y, Y4.y, Z4.y, qx, qy, qz));
                    D4.z = fminf(D4.z, npdist(X4.z, Y4.z, Z4.z, qx, qy, qz));
                    D4.w = fminf(D4.w, npdist(X4.w, Y4.w, Z4.w, qx, qy, qz));
                }
                ((float4*)Db)[vi] = D4;
                atomicAdd(&hist[__float_as_uint(D4.x) >> 19], 1u);
                atomicAdd(&hist[__float_as_uint(D4.y) >> 19], 1u);
                atomicAdd(&hist[__float_as_uint(D4.z) >> 19], 1u);
                atomicAdd(&hist[__float_as_uint(D4.w) >> 19], 1u);
                const int pp = vi << 2;         // original index (ascending)
                if (D4.x > rv) { rv = D4.x; roi = pp; }
                if (D4.y > rv) { rv = D4.y; roi = pp + 1; }
                if (D4.z > rv) { rv = D4.z; roi = pp + 2; }
                if (D4.w > rv) { rv = D4.w; roi = pp + 3; }
            }
            __syncthreads();                    // hist complete
            // global argmax (value desc, orig idx asc)
            #pragma unroll
            for (int m = 1; m < 64; m <<= 1) {
                const float ov = __shfl_xor(rv, m, 64);
                const int   oo = __shfl_xor(roi, m, 64);
                if (ov > rv || (ov == rv && oo < roi)) { rv = ov; roi = oo; }
            }
            if (lane == 0) { redv[bank][w] = rv; redi[bank][w] = roi; }
            __syncthreads();
            {
                float vv = (lane < NW2) ? redv[bank][lane] : NEG;
                int   jo = (lane < NW2) ? redi[bank][lane] : 0x7FFFFFFF;
                #pragma unroll
                for (int m = 1; m < NW2; m <<= 1) {
                    const float ov = __shfl_xor(vv, m, 64);
                    const int   oo = __shfl_xor(jo, m, 64);
                    if (ov > vv || (ov == vv && oo < jo)) { vv = ov; jo = oo; }
                }
                roi = __shfl(jo, 0, 64);
            }
            if (t == 0) { wx_s = Xb[roi]; wy_s = Yb[roi]; wz_s = Zb[roi]; }

            // suffix counts over 4096 bins (8/thread) -> theta (rank<=CAP)
            const unsigned h0 = hist[8*t+0], h1 = hist[8*t+1];
            const unsigned h2 = hist[8*t+2], h3 = hist[8*t+3];
            const unsigned h4 = hist[8*t+4], h5 = hist[8*t+5];
            const unsigned h6 = hist[8*t+6], h7 = hist[8*t+7];
            sc[t] = h0+h1+h2+h3+h4+h5+h6+h7;
            __syncthreads();
            for (int off = 1; off < FPS2_T; off <<= 1) {
                const unsigned ad = (t + off < FPS2_T) ? sc[t + off] : 0u;
                __syncthreads();
                sc[t] += ad;
                __syncthreads();
            }
            const unsigned tail = (t < FPS2_T-1) ? sc[t+1] : 0u;
            const unsigned S7 = h7 + tail;
            const unsigned S6 = h6 + S7;
            const unsigned S5 = h5 + S6;
            const unsigned S4 = h4 + S5;
            const unsigned S3 = h3 + S4;
            const unsigned S2 = h2 + S3;
            const unsigned S1 = h1 + S2;
            const unsigned S0 = h0 + S1;
            int bb = 0x7FFFFFFF;
            if      (S0 <= CAP) bb = 8*t + 0;
            else if (S1 <= CAP) bb = 8*t + 1;
            else if (S2 <= CAP) bb = 8*t + 2;
            else if (S3 <= CAP) bb = 8*t + 3;
            else if (S4 <= CAP) bb = 8*t + 4;
            else if (S5 <= CAP) bb = 8*t + 5;
            else if (S6 <= CAP) bb = 8*t + 6;
            else if (S7 <= CAP) bb = 8*t + 7;
            if (bb != 0x7FFFFFFF) atomicMin(&bstar_s, bb);
            __syncthreads();
            const int bstar = bstar_s;
            theta = (bstar == 0x7FFFFFFF) ? __builtin_inff()
                                          : __uint_as_float((unsigned)bstar << 19);
            wx = wx_s; wy = wy_s; wz = wz_s;
            if (t == 0) {
                po[s*3+0] = wx; po[s*3+1] = wy; po[s*3+2] = wz;
                pendx[0] = wx; pendy[0] = wy; pendz[0] = wz;
                npend_s = 1;
            }
            // pass 2: collect C = {d > theta} (<= CAP by construction)
            for (int vi = t; vi < NVEC4; vi += FPS2_T) {
                const float4 X4 = ((const float4*)Xb)[vi];
                const float4 Y4 = ((const float4*)Yb)[vi];
                const float4 Z4 = ((const float4*)Zb)[vi];
                const float4 D4 = ((float4*)Db)[vi];
                const int pp = vi << 2;
                CPAK(X4.x, Y4.x, Z4.x, D4.x, pp + 0)
                CPAK(X4.y, Y4.y, Z4.y, D4.y, pp + 1)
                CPAK(X4.z, Y4.z, Z4.z, D4.z, pp + 2)
                CPAK(X4.w, Y4.w, Z4.w, D4.w, pp + 3)
            }
            __syncthreads();
            candN = (int)ccnt;
        }
    }
}

extern "C" void kernel_launch(void* const* d_in, const int* in_sizes, int n_in,
                              void* d_out, int out_size, void* d_ws, size_t ws_size,
                              hipStream_t stream)
{
    const float* feat    = (const float*)d_in[0];
    const float* partial = (const float*)d_in[1];
    const float* ps_w    = (const float*)d_in[2];
    const float* ps_b    = (const float*)d_in[3];
    const float* m1_w1   = (const float*)d_in[4];
    const float* m1_b1   = (const float*)d_in[5];
    const float* m1_w2   = (const float*)d_in[6];
    const float* m1_b2   = (const float*)d_in[7];
    const float* m1_ws   = (const float*)d_in[8];
    const float* m1_bs   = (const float*)d_in[9];
    const float* m2_w1   = (const float*)d_in[10];
    const float* m2_b1   = (const float*)d_in[11];
    const float* m2_w2   = (const float*)d_in[12];
    const float* m2_b2   = (const float*)d_in[13];
    const float* m2_ws   = (const float*)d_in[14];
    const float* m2_bs   = (const float*)d_in[15];
    const float* m3_w1   = (const float*)d_in[16];
    const float* m3_b1   = (const float*)d_in[17];
    const float* m3_w2   = (const float*)d_in[18];
    const float* m3_b2   = (const float*)d_in[19];
    const float* m3_ws   = (const float*)d_in[20];
    const float* m3_bs   = (const float*)d_in[21];
    const float* m4_w1   = (const float*)d_in[22];
    const float* m4_b1   = (const float*)d_in[23];
    const float* m4_w2   = (const float*)d_in[24];
    const float* m4_b2   = (const float*)d_in[25];

    float* ws = (float*)d_ws;
    float* XYZ = ws;               // 3,170,304 floats (SoA per batch)
    float* A  = ws + 3170304;      // 1,048,576
    float* B  = ws + 4218880;      // 1,048,576
    float* C  = ws + 5267456;      // 1,048,576
    float* FB = ws + 6316032;      // 16,384
    float* Dg = ws + 6332416;      // 32*33024 = 1,056,768 floats (d array)

    float* out = (float*)d_out;   // [0,24576) pcd ; [24576,73728) p0

    k_ps  <<<128,  256, 0, stream>>>(feat, ps_w, ps_b, A);
    k_fb  <<<64,   256, 0, stream>>>(feat, m1_w1, m1_ws, m3_w1, m3_ws, FB);
    k_copy<<<4096, 256, 0, stream>>>(partial, XYZ);

    // m1 (fr folded into FB)
    k_conv<<<32*128, 256, 0, stream>>>(A, m1_w1, m1_b1, FB,       nullptr, B, 128, 128, 640, 1);
    k_conv<<<32*128, 256, 0, stream>>>(A, m1_ws, m1_bs, FB+4096,  nullptr, C, 128, 128, 640, 0);
    k_conv<<<32*128, 256, 0, stream>>>(B, m1_w2, m1_b2, nullptr,  C,       A, 128, 128, 128, 0);
    // m2
    k_conv<<<32*64,  256, 0, stream>>>(A, m2_w1, m2_b1, nullptr,  nullptr, B, 64,  128, 128, 1);
    k_conv<<<32*128, 256, 0, stream>>>(A, m2_ws, m2_bs, nullptr,  nullptr, C, 128, 128, 128, 0);
    k_conv<<<32*128, 256, 0, stream>>>(B, m2_w2, m2_b2, nullptr,  C,       A, 128, 64,  64,  0);
    // m3 (fr folded)
    k_conv<<<32*128, 256, 0, stream>>>(A, m3_w1, m3_b1, FB+8192,  nullptr, B, 128, 128, 640, 1);
    k_conv<<<32*128, 256, 0, stream>>>(A, m3_ws, m3_bs, FB+12288, nullptr, C, 128, 128, 640, 0);
    k_conv<<<32*128, 256, 0, stream>>>(B, m3_w2, m3_b2, nullptr,  C,       A, 128, 128, 128, 0);
    // m4
    k_conv<<<32*64,  256, 0, stream>>>(A, m4_w1, m4_b1, nullptr,  nullptr, B, 64,  128, 128, 1);
    k_conv<<<32*3,   256, 0, stream>>>(B, m4_w2, m4_b2, nullptr,  nullptr, C, 3,   64,  64,  0);

    k_pcd <<<32, 256, 0, stream>>>(C, out, XYZ);
    k_fps <<<32, FPS2_T, 0, stream>>>(XYZ, Dg, out + 24576);
}